// Round 1
// baseline (630.473 us; speedup 1.0000x reference)
//
#include <hip/hip_runtime.h>

#define N_NODESC 50000
#define NEMBEDC 128
#define HDIMC 256
#define NCLASSC 40

// ---------------- ws layout (bytes) ----------------
// deg    int[50176]   @ 0
// offs   int[50176]   @ 200704
// cursor int[50176]   @ 401408
// bsum   int[128]     @ 602112
// boff   int[128]     @ 602624
// flag   int          @ 603136
// bmat   f32[256*256] @ 603392
// csr    int[800000]  @ 865536
// mean   f32[50000*128] @ 4065536   (ends at ~29.7 MB)

// Detect whether edge_index arrived as int64 (odd int32 words all zero) or int32.
__global__ void k_detect(const int* __restrict__ e32, int* __restrict__ flag) {
  __shared__ int any;
  if (threadIdx.x == 0) any = 0;
  __syncthreads();
  int local = 0;
  for (int i = threadIdx.x; i < 2048; i += blockDim.x)
    if (e32[2 * i + 1] != 0) local = 1;
  if (local) atomicOr(&any, 1);
  __syncthreads();
  if (threadIdx.x == 0) *flag = any ? 0 : 1;  // 1 => int64 layout
}

__global__ void k_count(const int* __restrict__ e32, const int* __restrict__ flag,
                        int E, int* __restrict__ deg) {
  int i = blockIdx.x * 256 + threadIdx.x;
  if (i >= E) return;
  int dst = (*flag) ? e32[2 * E + 2 * i] : e32[E + i];
  atomicAdd(&deg[dst], 1);
}

__global__ void k_scan_partial(const int* __restrict__ deg, int* __restrict__ bsum) {
  __shared__ int s[512];
  int tid = threadIdx.x;
  s[tid] = deg[blockIdx.x * 512 + tid];
  __syncthreads();
  for (int off = 256; off > 0; off >>= 1) {
    if (tid < off) s[tid] += s[tid + off];
    __syncthreads();
  }
  if (tid == 0) bsum[blockIdx.x] = s[0];
}

__global__ void k_scan_bsum(const int* __restrict__ bsum, int* __restrict__ boff) {
  __shared__ int s[128];
  int tid = threadIdx.x;
  int v = (tid < 98) ? bsum[tid] : 0;
  s[tid] = v;
  __syncthreads();
  for (int off = 1; off < 128; off <<= 1) {
    int t = (tid >= off) ? s[tid - off] : 0;
    __syncthreads();
    s[tid] += t;
    __syncthreads();
  }
  boff[tid] = s[tid] - v;  // exclusive
}

__global__ void k_scan_final(const int* __restrict__ deg, const int* __restrict__ boff,
                             int* __restrict__ offs, int* __restrict__ cursor) {
  __shared__ int s[512];
  int tid = threadIdx.x;
  int g = blockIdx.x * 512 + tid;
  int v = deg[g];
  s[tid] = v;
  __syncthreads();
  for (int off = 1; off < 512; off <<= 1) {
    int t = (tid >= off) ? s[tid - off] : 0;
    __syncthreads();
    s[tid] += t;
    __syncthreads();
  }
  int e = s[tid] - v + boff[blockIdx.x];
  offs[g] = e;
  cursor[g] = e;
}

__global__ void k_fill(const int* __restrict__ e32, const int* __restrict__ flag,
                       int E, int* __restrict__ cursor, int* __restrict__ csr) {
  int i = blockIdx.x * 256 + threadIdx.x;
  if (i >= E) return;
  int is64 = *flag;
  int src = is64 ? e32[2 * i] : e32[i];
  int dst = is64 ? e32[2 * E + 2 * i] : e32[E + i];
  int p = atomicAdd(&cursor[dst], 1);
  csr[p] = src;
}

// One wave per node: 64 lanes x float2 = full 512B row per iteration.
__global__ void k_aggregate(const float* __restrict__ x, const int* __restrict__ csr,
                            const int* __restrict__ offs, const int* __restrict__ deg,
                            float* __restrict__ mean) {
  int wave = threadIdx.x >> 6;
  int lane = threadIdx.x & 63;
  int node = blockIdx.x * 4 + wave;
  if (node >= N_NODESC) return;
  int beg = offs[node];
  int d = deg[node];
  const float2* x2 = (const float2*)x;
  float ax = 0.f, ay = 0.f;
  for (int e = 0; e < d; ++e) {
    int s = csr[beg + e];
    float2 v = x2[s * 64 + lane];
    ax += v.x;
    ay += v.y;
  }
  float inv = 1.0f / (float)(d > 0 ? d : 1);
  float2 r;
  r.x = ax * inv;
  r.y = ay * inv;
  ((float2*)mean)[node * 64 + lane] = r;
}

// bmat[k][j]: k<128 -> W_l[j][k], k>=128 -> W_r[j][k-128]  (k-major for coalesced tiles)
__global__ void k_build_b(const float* __restrict__ W_l, const float* __restrict__ W_r,
                          float* __restrict__ bmat) {
  int i = blockIdx.x * 256 + threadIdx.x;
  int k = i >> 8, j = i & 255;
  bmat[i] = (k < 128) ? W_l[j * 128 + k] : W_r[j * 128 + (k - 128)];
}

__global__ void k_init_out(const float* __restrict__ b_mlp, float* __restrict__ out) {
  int i = blockIdx.x * 256 + threadIdx.x;
  if (i < N_NODESC * NCLASSC) out[i] = b_mlp[i % NCLASSC];
}

// Fused: h-tile[64 nodes][64 hdim] = [mean|x] @ bmat, +b_l, relu, then partial
// out += relu(h) @ W_mlp^T chunk, atomically accumulated (out pre-set to b_mlp).
__global__ __launch_bounds__(256) void k_fused(
    const float* __restrict__ mean, const float* __restrict__ x,
    const float* __restrict__ bmat, const float* __restrict__ b_l,
    const float* __restrict__ W_mlp, float* __restrict__ out) {
  __shared__ float As[32][64];   // A tile transposed: As[kk][m]
  __shared__ float Bs[32][64];   // Bs[kk][j]
  __shared__ float Hs[64][65];   // relu'd h tile, padded (2-way max)
  __shared__ float Wm[40][64];   // W_mlp chunk
  int t = threadIdx.x;
  int m0 = blockIdx.x * 64;
  int j0 = blockIdx.y * 64;
  for (int i = t; i < 40 * 64; i += 256) {
    int c = i >> 6, j = i & 63;
    Wm[c][j] = W_mlp[c * HDIMC + j0 + j];
  }
  int tx = t & 15, ty = t >> 4;
  float acc[4][4] = {};
  for (int kt = 0; kt < 256; kt += 32) {
    const float* Asrc = (kt < 128) ? mean : x;  // virtual concat [mean | x]
    int kb = (kt < 128) ? kt : kt - 128;
#pragma unroll
    for (int r = 0; r < 2; ++r) {
      int f = t + r * 256;       // 0..511 covers 64x8 float4
      int m = f >> 3;
      int k4 = (f & 7) << 2;
      float4 v = make_float4(0.f, 0.f, 0.f, 0.f);
      int node = m0 + m;
      if (node < N_NODESC) v = *(const float4*)(Asrc + node * NEMBEDC + kb + k4);
      As[k4 + 0][m] = v.x;
      As[k4 + 1][m] = v.y;
      As[k4 + 2][m] = v.z;
      As[k4 + 3][m] = v.w;
    }
#pragma unroll
    for (int r = 0; r < 2; ++r) {
      int f = t + r * 256;
      int kk = f >> 4;
      int j4 = (f & 15) << 2;
      *(float4*)&Bs[kk][j4] = *(const float4*)(bmat + (kt + kk) * HDIMC + j0 + j4);
    }
    __syncthreads();
#pragma unroll
    for (int kk = 0; kk < 32; ++kk) {
      float4 a4 = *(const float4*)&As[kk][ty << 2];
      float4 b4 = *(const float4*)&Bs[kk][tx << 2];
      float av[4] = {a4.x, a4.y, a4.z, a4.w};
      float bv[4] = {b4.x, b4.y, b4.z, b4.w};
#pragma unroll
      for (int i = 0; i < 4; ++i)
#pragma unroll
        for (int j = 0; j < 4; ++j) acc[i][j] += av[i] * bv[j];
    }
    __syncthreads();
  }
#pragma unroll
  for (int i = 0; i < 4; ++i) {
#pragma unroll
    for (int j = 0; j < 4; ++j) {
      int jj = j0 + (tx << 2) + j;
      float h = acc[i][j] + b_l[jj];
      Hs[(ty << 2) + i][(tx << 2) + j] = h > 0.f ? h : 0.f;
    }
  }
  __syncthreads();
  // epilogue: lane = node row, wave = 10-class chunk; Wm reads are wave-uniform (broadcast)
  int lane = t & 63, w = t >> 6;
  int c0 = w * 10;
  float oacc[10];
#pragma unroll
  for (int c = 0; c < 10; ++c) oacc[c] = 0.f;
  for (int j = 0; j < 64; ++j) {
    float h = Hs[lane][j];
#pragma unroll
    for (int c = 0; c < 10; ++c) oacc[c] += h * Wm[c0 + c][j];
  }
  int node = m0 + lane;
  if (node < N_NODESC) {
#pragma unroll
    for (int c = 0; c < 10; ++c) atomicAdd(&out[node * NCLASSC + c0 + c], oacc[c]);
  }
}

extern "C" void kernel_launch(void* const* d_in, const int* in_sizes, int n_in,
                              void* d_out, int out_size, void* d_ws, size_t ws_size,
                              hipStream_t stream) {
  const float* x     = (const float*)d_in[0];
  const float* W_l   = (const float*)d_in[1];
  const float* b_l   = (const float*)d_in[2];
  const float* W_r   = (const float*)d_in[3];
  const float* W_mlp = (const float*)d_in[4];
  const float* b_mlp = (const float*)d_in[5];
  const int*   e32   = (const int*)d_in[6];
  int E = in_sizes[6] / 2;
  float* out = (float*)d_out;

  char* ws = (char*)d_ws;
  int* deg    = (int*)(ws + 0);
  int* offs   = (int*)(ws + 200704);
  int* cursor = (int*)(ws + 401408);
  int* bsum   = (int*)(ws + 602112);
  int* boff   = (int*)(ws + 602624);
  int* flag   = (int*)(ws + 603136);
  float* bmat = (float*)(ws + 603392);
  int* csr    = (int*)(ws + 865536);
  float* mean = (float*)(ws + 4065536);

  hipMemsetAsync(ws, 0, 603392, stream);
  k_detect<<<1, 256, 0, stream>>>(e32, flag);
  int eg = (E + 255) / 256;
  k_count<<<eg, 256, 0, stream>>>(e32, flag, E, deg);
  k_scan_partial<<<98, 512, 0, stream>>>(deg, bsum);
  k_scan_bsum<<<1, 128, 0, stream>>>(bsum, boff);
  k_scan_final<<<98, 512, 0, stream>>>(deg, boff, offs, cursor);
  k_fill<<<eg, 256, 0, stream>>>(e32, flag, E, cursor, csr);
  k_aggregate<<<(N_NODESC + 3) / 4, 256, 0, stream>>>(x, csr, offs, deg, mean);
  k_build_b<<<256, 256, 0, stream>>>(W_l, W_r, bmat);
  k_init_out<<<(N_NODESC * NCLASSC + 255) / 256, 256, 0, stream>>>(b_mlp, out);
  dim3 g(782, 4);
  k_fused<<<g, 256, 0, stream>>>(mean, x, bmat, b_l, W_mlp, out);
}

// Round 2
// 235.180 us; speedup vs baseline: 2.6808x; 2.6808x over previous
//
#include <hip/hip_runtime.h>

#define N_NODESC 50000
#define NEMBEDC 128
#define HDIMC 256
#define NCLASSC 40

typedef short short8v __attribute__((ext_vector_type(8)));
typedef float float4v __attribute__((ext_vector_type(4)));

// ---------------- ws layout (bytes) ----------------
// deg     int[50176]    @ 0
// offs    int[50176]    @ 200704
// cursor  int[50176]    @ 401408   (reused AFTER k_fill: wmlp_hi @401408, wmlp_lo @425984)
// bsum    int[128]      @ 602112
// boff    int[128]      @ 602624
// flag    int           @ 603136
// bmat_hi bf16[65536]   @ 603392   (fragment-ordered)
// bmat_lo bf16[65536]   @ 734464
// csr     int[800000]   @ 865536
// mean    f32[50000*128]@ 4065536  (ends 29665536)

__device__ __forceinline__ void bsplit(float f, short* hi, short* lo) {
  unsigned u = __builtin_bit_cast(unsigned, f);
  unsigned hb = (u + 0x7FFFu + ((u >> 16) & 1u)) >> 16;
  *hi = (short)hb;
  float hf = __builtin_bit_cast(float, hb << 16);
  float r = f - hf;
  unsigned u2 = __builtin_bit_cast(unsigned, r);
  *lo = (short)((u2 + 0x7FFFu + ((u2 >> 16) & 1u)) >> 16);
}

__global__ void k_detect(const int* __restrict__ e32, int* __restrict__ flag) {
  __shared__ int any;
  if (threadIdx.x == 0) any = 0;
  __syncthreads();
  int local = 0;
  for (int i = threadIdx.x; i < 2048; i += blockDim.x)
    if (e32[2 * i + 1] != 0) local = 1;
  if (local) atomicOr(&any, 1);
  __syncthreads();
  if (threadIdx.x == 0) *flag = any ? 0 : 1;  // 1 => int64 layout
}

__global__ void k_count(const int* __restrict__ e32, const int* __restrict__ flag,
                        int E, int* __restrict__ deg) {
  int i = blockIdx.x * 256 + threadIdx.x;
  if (i >= E) return;
  int dst = (*flag) ? e32[2 * E + 2 * i] : e32[E + i];
  atomicAdd(&deg[dst], 1);
}

__global__ void k_scan_partial(const int* __restrict__ deg, int* __restrict__ bsum) {
  __shared__ int s[512];
  int tid = threadIdx.x;
  s[tid] = deg[blockIdx.x * 512 + tid];
  __syncthreads();
  for (int off = 256; off > 0; off >>= 1) {
    if (tid < off) s[tid] += s[tid + off];
    __syncthreads();
  }
  if (tid == 0) bsum[blockIdx.x] = s[0];
}

__global__ void k_scan_bsum(const int* __restrict__ bsum, int* __restrict__ boff) {
  __shared__ int s[128];
  int tid = threadIdx.x;
  int v = (tid < 98) ? bsum[tid] : 0;
  s[tid] = v;
  __syncthreads();
  for (int off = 1; off < 128; off <<= 1) {
    int t = (tid >= off) ? s[tid - off] : 0;
    __syncthreads();
    s[tid] += t;
    __syncthreads();
  }
  boff[tid] = s[tid] - v;  // exclusive
}

__global__ void k_scan_final(const int* __restrict__ deg, const int* __restrict__ boff,
                             int* __restrict__ offs, int* __restrict__ cursor) {
  __shared__ int s[512];
  int tid = threadIdx.x;
  int g = blockIdx.x * 512 + tid;
  int v = deg[g];
  s[tid] = v;
  __syncthreads();
  for (int off = 1; off < 512; off <<= 1) {
    int t = (tid >= off) ? s[tid - off] : 0;
    __syncthreads();
    s[tid] += t;
    __syncthreads();
  }
  int e = s[tid] - v + boff[blockIdx.x];
  offs[g] = e;
  cursor[g] = e;
}

__global__ void k_fill(const int* __restrict__ e32, const int* __restrict__ flag,
                       int E, int* __restrict__ cursor, int* __restrict__ csr) {
  int i = blockIdx.x * 256 + threadIdx.x;
  if (i >= E) return;
  int is64 = *flag;
  int src = is64 ? e32[2 * i] : e32[i];
  int dst = is64 ? e32[2 * E + 2 * i] : e32[E + i];
  int p = atomicAdd(&cursor[dst], 1);
  csr[p] = src;
}

// One wave per node: 64 lanes x float2 = full 512B row per iteration.
__global__ void k_aggregate(const float* __restrict__ x, const int* __restrict__ csr,
                            const int* __restrict__ offs, const int* __restrict__ deg,
                            float* __restrict__ mean) {
  int wave = threadIdx.x >> 6;
  int lane = threadIdx.x & 63;
  int node = blockIdx.x * 4 + wave;
  if (node >= N_NODESC) return;
  int beg = offs[node];
  int d = deg[node];
  const float2* x2 = (const float2*)x;
  float ax = 0.f, ay = 0.f;
  for (int e = 0; e < d; ++e) {
    int s = csr[beg + e];
    float2 v = x2[s * 64 + lane];
    ax += v.x;
    ay += v.y;
  }
  float inv = 1.0f / (float)(d > 0 ? d : 1);
  float2 r;
  r.x = ax * inv;
  r.y = ay * inv;
  ((float2*)mean)[node * 64 + lane] = r;
}

// B = [W_l | W_r] as bf16 hi/lo in MFMA fragment order:
// elem (ks, nf, lane, e) = B[k = ks*32 + (lane>>4)*8 + e][n = nf*16 + (lane&15)]
__global__ void k_build_b(const float* __restrict__ W_l, const float* __restrict__ W_r,
                          short* __restrict__ bh, short* __restrict__ bl) {
  int i = blockIdx.x * 256 + threadIdx.x;  // < 65536
  int e = i & 7, l = (i >> 3) & 63, nf = (i >> 9) & 15, ks = i >> 13;
  int k = ks * 32 + (l >> 4) * 8 + e;
  int n = nf * 16 + (l & 15);
  float v = (k < 128) ? W_l[n * 128 + k] : W_r[n * 128 + (k - 128)];
  short h, lo;
  bsplit(v, &h, &lo);
  bh[i] = h;
  bl[i] = lo;
}

// W_mlp (padded to 48 rows) as bf16 hi/lo fragment order: [ks(8)][nf(3)][lane][8]
__global__ void k_build_w(const float* __restrict__ W_mlp,
                          short* __restrict__ wh, short* __restrict__ wl) {
  int i = blockIdx.x * 256 + threadIdx.x;  // < 12288
  int e = i & 7, l = (i >> 3) & 63, g = i >> 9;  // g < 24
  int nf = g % 3, ks = g / 3;
  int k = ks * 32 + (l >> 4) * 8 + e;
  int n = nf * 16 + (l & 15);
  float v = (n < NCLASSC) ? W_mlp[n * HDIMC + k] : 0.f;
  short h, lo;
  bsplit(v, &h, &lo);
  wh[i] = h;
  wl[i] = lo;
}

// Fused GEMM1+GEMM2 via MFMA, split-bf16 3-pass.
// Block: 64 nodes x full 256 hdim. 8 waves, wave tile 32x64.
__global__ __launch_bounds__(512, 4) void k_fused_mfma(
    const float* __restrict__ mean, const float* __restrict__ x,
    const short* __restrict__ bmh, const short* __restrict__ bml,
    const short* __restrict__ wmh, const short* __restrict__ wml,
    const float* __restrict__ b_l, const float* __restrict__ b_mlp,
    float* __restrict__ out) {
  __shared__ short sh[32768];  // 64 KB: hi [0,16384), lo [16384,32768); reused for h
  int t = threadIdx.x;
  int m0 = blockIdx.x * 64;

  // ---- stage A = [mean | x] rows m0..m0+63 as bf16 hi/lo, XOR-swizzled ----
#pragma unroll
  for (int r = 0; r < 4; ++r) {
    int c = t + 512 * r;          // chunk id: 64 rows x 32 chunks-of-8
    int row = c >> 5, kc = c & 31;
    int node = m0 + row;
    float4 v0 = make_float4(0.f, 0.f, 0.f, 0.f), v1 = v0;
    if (node < N_NODESC) {
      const float* src = (kc < 16) ? (mean + (size_t)node * 128 + kc * 8)
                                   : (x + (size_t)node * 128 + (kc - 16) * 8);
      v0 = *(const float4*)src;
      v1 = *(const float4*)(src + 4);
    }
    float f[8] = {v0.x, v0.y, v0.z, v0.w, v1.x, v1.y, v1.z, v1.w};
    short8v hi8, lo8;
#pragma unroll
    for (int i = 0; i < 8; ++i) {
      short h, lo;
      bsplit(f[i], &h, &lo);
      hi8[i] = h;
      lo8[i] = lo;
    }
    int sidx = row * 256 + ((kc ^ (row & 7)) << 3);
    *(short8v*)&sh[sidx] = hi8;
    *(short8v*)&sh[16384 + sidx] = lo8;
  }
  __syncthreads();

  int w = t >> 6, l = t & 63;
  int wm = w >> 2, wn = w & 3;   // wave tile: rows wm*32..+32, cols wn*64..+64
  int lr = l & 15, lg = l >> 4;

  float4v acc[2][4];
#pragma unroll
  for (int mi = 0; mi < 2; ++mi)
#pragma unroll
    for (int nj = 0; nj < 4; ++nj) acc[mi][nj] = (float4v){0.f, 0.f, 0.f, 0.f};

  // ---- GEMM1: h = A @ B, K=256 in 8 steps of 32 ----
  for (int ks = 0; ks < 8; ++ks) {
    short8v ah[2], al[2];
#pragma unroll
    for (int mi = 0; mi < 2; ++mi) {
      int row = wm * 32 + mi * 16 + lr;
      int kc = ks * 4 + lg;
      int sidx = row * 256 + ((kc ^ (row & 7)) << 3);
      ah[mi] = *(short8v*)&sh[sidx];
      al[mi] = *(short8v*)&sh[16384 + sidx];
    }
    short8v bh[4], blo[4];
#pragma unroll
    for (int nj = 0; nj < 4; ++nj) {
      int nf = wn * 4 + nj;
      int fi = ((ks * 16 + nf) * 64 + l) * 8;
      bh[nj] = *(const short8v*)&bmh[fi];
      blo[nj] = *(const short8v*)&bml[fi];
    }
#pragma unroll
    for (int mi = 0; mi < 2; ++mi)
#pragma unroll
      for (int nj = 0; nj < 4; ++nj) {
        acc[mi][nj] = __builtin_amdgcn_mfma_f32_16x16x32_bf16(ah[mi], bh[nj], acc[mi][nj], 0, 0, 0);
        acc[mi][nj] = __builtin_amdgcn_mfma_f32_16x16x32_bf16(ah[mi], blo[nj], acc[mi][nj], 0, 0, 0);
        acc[mi][nj] = __builtin_amdgcn_mfma_f32_16x16x32_bf16(al[mi], bh[nj], acc[mi][nj], 0, 0, 0);
      }
  }
  __syncthreads();  // all waves done reading A

  // ---- epilogue 1: h = relu(acc + b_l) -> bf16 hi/lo back into sh ----
#pragma unroll
  for (int mi = 0; mi < 2; ++mi)
#pragma unroll
    for (int nj = 0; nj < 4; ++nj) {
      int col = wn * 64 + nj * 16 + lr;
      float bb = b_l[col];
#pragma unroll
      for (int r = 0; r < 4; ++r) {
        int row = wm * 32 + mi * 16 + lg * 4 + r;
        float v = acc[mi][nj][r] + bb;
        v = fmaxf(v, 0.f);
        short h, lo;
        bsplit(v, &h, &lo);
        int kc2 = col >> 3;
        int sidx = row * 256 + ((kc2 ^ (row & 7)) << 3) + (col & 7);
        sh[sidx] = h;
        sh[16384 + sidx] = lo;
      }
    }
  __syncthreads();

  // ---- GEMM2: out = relu(h) @ Wmlp^T (48 padded cols), K=256 ----
  int mf = w & 3;            // waves 0-3: nf {0,1}; waves 4-7: nf {2}
  float4v a2[2];
  a2[0] = (float4v){0.f, 0.f, 0.f, 0.f};
  a2[1] = a2[0];
  for (int ks = 0; ks < 8; ++ks) {
    int row = mf * 16 + lr;
    int kc = ks * 4 + lg;
    int sidx = row * 256 + ((kc ^ (row & 7)) << 3);
    short8v hh = *(short8v*)&sh[sidx];
    short8v hl = *(short8v*)&sh[16384 + sidx];
#pragma unroll
    for (int u = 0; u < 2; ++u) {
      if (w >= 4 && u > 0) break;
      int nf = (w < 4) ? u : 2;
      int fi = ((ks * 3 + nf) * 64 + l) * 8;
      short8v wh = *(const short8v*)&wmh[fi];
      short8v wlo = *(const short8v*)&wml[fi];
      a2[u] = __builtin_amdgcn_mfma_f32_16x16x32_bf16(hh, wh, a2[u], 0, 0, 0);
      a2[u] = __builtin_amdgcn_mfma_f32_16x16x32_bf16(hl, wh, a2[u], 0, 0, 0);
      a2[u] = __builtin_amdgcn_mfma_f32_16x16x32_bf16(hh, wlo, a2[u], 0, 0, 0);
    }
  }
#pragma unroll
  for (int u = 0; u < 2; ++u) {
    if (w >= 4 && u > 0) break;
    int nf = (w < 4) ? u : 2;
    int col = nf * 16 + lr;
    if (col < NCLASSC) {
      float bb = b_mlp[col];
#pragma unroll
      for (int r = 0; r < 4; ++r) {
        int node = m0 + mf * 16 + lg * 4 + r;
        if (node < N_NODESC) out[node * NCLASSC + col] = a2[u][r] + bb;
      }
    }
  }
}

extern "C" void kernel_launch(void* const* d_in, const int* in_sizes, int n_in,
                              void* d_out, int out_size, void* d_ws, size_t ws_size,
                              hipStream_t stream) {
  const float* x     = (const float*)d_in[0];
  const float* W_l   = (const float*)d_in[1];
  const float* b_l   = (const float*)d_in[2];
  const float* W_r   = (const float*)d_in[3];
  const float* W_mlp = (const float*)d_in[4];
  const float* b_mlp = (const float*)d_in[5];
  const int*   e32   = (const int*)d_in[6];
  int E = in_sizes[6] / 2;
  float* out = (float*)d_out;

  char* ws = (char*)d_ws;
  int* deg     = (int*)(ws + 0);
  int* offs    = (int*)(ws + 200704);
  int* cursor  = (int*)(ws + 401408);
  short* wmh   = (short*)(ws + 401408);  // overlays cursor AFTER k_fill
  short* wml   = (short*)(ws + 425984);
  int* bsum    = (int*)(ws + 602112);
  int* boff    = (int*)(ws + 602624);
  int* flag    = (int*)(ws + 603136);
  short* bmh   = (short*)(ws + 603392);
  short* bml   = (short*)(ws + 734464);
  int* csr     = (int*)(ws + 865536);
  float* mean  = (float*)(ws + 4065536);

  hipMemsetAsync(ws, 0, 603392, stream);
  k_detect<<<1, 256, 0, stream>>>(e32, flag);
  int eg = (E + 255) / 256;
  k_count<<<eg, 256, 0, stream>>>(e32, flag, E, deg);
  k_scan_partial<<<98, 512, 0, stream>>>(deg, bsum);
  k_scan_bsum<<<1, 128, 0, stream>>>(bsum, boff);
  k_scan_final<<<98, 512, 0, stream>>>(deg, boff, offs, cursor);
  k_fill<<<eg, 256, 0, stream>>>(e32, flag, E, cursor, csr);
  k_build_b<<<256, 256, 0, stream>>>(W_l, W_r, bmh, bml);
  k_build_w<<<48, 256, 0, stream>>>(W_mlp, wmh, wml);   // cursor dead after k_fill
  k_aggregate<<<(N_NODESC + 3) / 4, 256, 0, stream>>>(x, csr, offs, deg, mean);
  k_fused_mfma<<<782, 512, 0, stream>>>(mean, x, bmh, bml, wmh, wml, b_l, b_mlp, out);
}

// Round 3
// 196.679 us; speedup vs baseline: 3.2056x; 1.1958x over previous
//
#include <hip/hip_runtime.h>

#define N_NODESC 50000
#define NEMBEDC 128
#define HDIMC 256
#define NCLASSC 40

typedef short short8v __attribute__((ext_vector_type(8)));
typedef float float4v __attribute__((ext_vector_type(4)));

// ---------------- ws layout (bytes) ----------------
// deg     int[50176]    @ 0
// offs    int[50176]    @ 200704
// cursor  int[50176]    @ 401408   (reused AFTER k_fill: wmlp_hi @401408, wmlp_lo @425984)
// bsum    int[128]      @ 602112
// boff    int[128]      @ 602624
// flag    int           @ 603136
// bmat_hi bf16[65536]   @ 603392   (fragment-ordered)
// bmat_lo bf16[65536]   @ 734464
// csr     int[800000]   @ 865536
// mean    f32[50000*128]@ 4065536  (ends 29665536)
// xb      bf16[6400000] @ 29665536 (ends 42465536) — only if ws_size permits

__device__ __forceinline__ void bsplit(float f, short* hi, short* lo) {
  unsigned u = __builtin_bit_cast(unsigned, f);
  unsigned hb = (u + 0x7FFFu + ((u >> 16) & 1u)) >> 16;
  *hi = (short)hb;
  float hf = __builtin_bit_cast(float, hb << 16);
  float r = f - hf;
  unsigned u2 = __builtin_bit_cast(unsigned, r);
  *lo = (short)((u2 + 0x7FFFu + ((u2 >> 16) & 1u)) >> 16);
}

__device__ __forceinline__ float blo(unsigned v) {
  return __builtin_bit_cast(float, v << 16);
}
__device__ __forceinline__ float bhi(unsigned v) {
  return __builtin_bit_cast(float, v & 0xFFFF0000u);
}

__global__ void k_detect(const int* __restrict__ e32, int* __restrict__ flag) {
  __shared__ int any;
  if (threadIdx.x == 0) any = 0;
  __syncthreads();
  int local = 0;
  for (int i = threadIdx.x; i < 2048; i += blockDim.x)
    if (e32[2 * i + 1] != 0) local = 1;
  if (local) atomicOr(&any, 1);
  __syncthreads();
  if (threadIdx.x == 0) *flag = any ? 0 : 1;  // 1 => int64 layout
}

__global__ void k_count(const int* __restrict__ e32, const int* __restrict__ flag,
                        int E, int* __restrict__ deg) {
  int i = blockIdx.x * 256 + threadIdx.x;
  if (i >= E) return;
  int dst = (*flag) ? e32[2 * E + 2 * i] : e32[E + i];
  atomicAdd(&deg[dst], 1);
}

__global__ void k_scan_partial(const int* __restrict__ deg, int* __restrict__ bsum) {
  __shared__ int s[512];
  int tid = threadIdx.x;
  s[tid] = deg[blockIdx.x * 512 + tid];
  __syncthreads();
  for (int off = 256; off > 0; off >>= 1) {
    if (tid < off) s[tid] += s[tid + off];
    __syncthreads();
  }
  if (tid == 0) bsum[blockIdx.x] = s[0];
}

__global__ void k_scan_bsum(const int* __restrict__ bsum, int* __restrict__ boff) {
  __shared__ int s[128];
  int tid = threadIdx.x;
  int v = (tid < 98) ? bsum[tid] : 0;
  s[tid] = v;
  __syncthreads();
  for (int off = 1; off < 128; off <<= 1) {
    int t = (tid >= off) ? s[tid - off] : 0;
    __syncthreads();
    s[tid] += t;
    __syncthreads();
  }
  boff[tid] = s[tid] - v;  // exclusive
}

__global__ void k_scan_final(const int* __restrict__ deg, const int* __restrict__ boff,
                             int* __restrict__ offs, int* __restrict__ cursor) {
  __shared__ int s[512];
  int tid = threadIdx.x;
  int g = blockIdx.x * 512 + tid;
  int v = deg[g];
  s[tid] = v;
  __syncthreads();
  for (int off = 1; off < 512; off <<= 1) {
    int t = (tid >= off) ? s[tid - off] : 0;
    __syncthreads();
    s[tid] += t;
    __syncthreads();
  }
  int e = s[tid] - v + boff[blockIdx.x];
  offs[g] = e;
  cursor[g] = e;
}

__global__ void k_fill(const int* __restrict__ e32, const int* __restrict__ flag,
                       int E, int* __restrict__ cursor, int* __restrict__ csr) {
  int i = blockIdx.x * 256 + threadIdx.x;
  if (i >= E) return;
  int is64 = *flag;
  int src = is64 ? e32[2 * i] : e32[i];
  int dst = is64 ? e32[2 * E + 2 * i] : e32[E + i];
  int p = atomicAdd(&cursor[dst], 1);
  csr[p] = src;
}

// x -> bf16 (RN), 8 elems/thread
__global__ void k_xbf16(const float* __restrict__ x, unsigned short* __restrict__ xb) {
  int i = (blockIdx.x * 256 + threadIdx.x) * 8;
  float4 a = *(const float4*)(x + i);
  float4 b = *(const float4*)(x + i + 4);
  float f[8] = {a.x, a.y, a.z, a.w, b.x, b.y, b.z, b.w};
  unsigned h[8];
#pragma unroll
  for (int j = 0; j < 8; ++j) {
    unsigned u = __builtin_bit_cast(unsigned, f[j]);
    h[j] = (u + 0x7FFFu + ((u >> 16) & 1u)) >> 16;
  }
  uint4 o;
  o.x = h[0] | (h[1] << 16);
  o.y = h[2] | (h[3] << 16);
  o.z = h[4] | (h[5] << 16);
  o.w = h[6] | (h[7] << 16);
  *(uint4*)(xb + i) = o;
}

// One wave per node, bf16 gather (256B/row), 4-deep MLP unroll.
__global__ __launch_bounds__(512) void k_aggregate_bf(
    const unsigned short* __restrict__ xb, const int* __restrict__ csr,
    const int* __restrict__ offs, const int* __restrict__ deg,
    float* __restrict__ mean) {
  int wave = threadIdx.x >> 6;
  int lane = threadIdx.x & 63;
  int node = blockIdx.x * 8 + wave;
  if (node >= N_NODESC) return;
  int beg = __builtin_amdgcn_readfirstlane(offs[node]);
  int d = __builtin_amdgcn_readfirstlane(deg[node]);
  const unsigned* xw = (const unsigned*)xb;
  float ax = 0.f, ay = 0.f;
  int e = 0;
  for (; e + 4 <= d; e += 4) {
    int s0 = csr[beg + e + 0];
    int s1 = csr[beg + e + 1];
    int s2 = csr[beg + e + 2];
    int s3 = csr[beg + e + 3];
    unsigned v0 = xw[s0 * 64 + lane];
    unsigned v1 = xw[s1 * 64 + lane];
    unsigned v2 = xw[s2 * 64 + lane];
    unsigned v3 = xw[s3 * 64 + lane];
    ax += blo(v0) + blo(v1) + blo(v2) + blo(v3);
    ay += bhi(v0) + bhi(v1) + bhi(v2) + bhi(v3);
  }
  for (; e < d; ++e) {
    unsigned v = xw[csr[beg + e] * 64 + lane];
    ax += blo(v);
    ay += bhi(v);
  }
  float inv = 1.0f / (float)(d > 0 ? d : 1);
  float2 r;
  r.x = ax * inv;
  r.y = ay * inv;
  ((float2*)mean)[node * 64 + lane] = r;
}

// Fallback: f32 gather (512B/row), 4-deep MLP unroll.
__global__ __launch_bounds__(512) void k_aggregate_f32(
    const float* __restrict__ x, const int* __restrict__ csr,
    const int* __restrict__ offs, const int* __restrict__ deg,
    float* __restrict__ mean) {
  int wave = threadIdx.x >> 6;
  int lane = threadIdx.x & 63;
  int node = blockIdx.x * 8 + wave;
  if (node >= N_NODESC) return;
  int beg = __builtin_amdgcn_readfirstlane(offs[node]);
  int d = __builtin_amdgcn_readfirstlane(deg[node]);
  const float2* x2 = (const float2*)x;
  float ax = 0.f, ay = 0.f;
  int e = 0;
  for (; e + 4 <= d; e += 4) {
    int s0 = csr[beg + e + 0];
    int s1 = csr[beg + e + 1];
    int s2 = csr[beg + e + 2];
    int s3 = csr[beg + e + 3];
    float2 v0 = x2[s0 * 64 + lane];
    float2 v1 = x2[s1 * 64 + lane];
    float2 v2 = x2[s2 * 64 + lane];
    float2 v3 = x2[s3 * 64 + lane];
    ax += v0.x + v1.x + v2.x + v3.x;
    ay += v0.y + v1.y + v2.y + v3.y;
  }
  for (; e < d; ++e) {
    float2 v = x2[csr[beg + e] * 64 + lane];
    ax += v.x;
    ay += v.y;
  }
  float inv = 1.0f / (float)(d > 0 ? d : 1);
  float2 r;
  r.x = ax * inv;
  r.y = ay * inv;
  ((float2*)mean)[node * 64 + lane] = r;
}

// B = [W_l | W_r] as bf16 hi/lo in MFMA fragment order:
// elem (ks, nf, lane, e) = B[k = ks*32 + (lane>>4)*8 + e][n = nf*16 + (lane&15)]
__global__ void k_build_b(const float* __restrict__ W_l, const float* __restrict__ W_r,
                          short* __restrict__ bh, short* __restrict__ bl) {
  int i = blockIdx.x * 256 + threadIdx.x;  // < 65536
  int e = i & 7, l = (i >> 3) & 63, nf = (i >> 9) & 15, ks = i >> 13;
  int k = ks * 32 + (l >> 4) * 8 + e;
  int n = nf * 16 + (l & 15);
  float v = (k < 128) ? W_l[n * 128 + k] : W_r[n * 128 + (k - 128)];
  short h, lo;
  bsplit(v, &h, &lo);
  bh[i] = h;
  bl[i] = lo;
}

// W_mlp (padded to 48 rows) as bf16 hi/lo fragment order: [ks(8)][nf(3)][lane][8]
__global__ void k_build_w(const float* __restrict__ W_mlp,
                          short* __restrict__ wh, short* __restrict__ wl) {
  int i = blockIdx.x * 256 + threadIdx.x;  // < 12288
  int e = i & 7, l = (i >> 3) & 63, g = i >> 9;  // g < 24
  int nf = g % 3, ks = g / 3;
  int k = ks * 32 + (l >> 4) * 8 + e;
  int n = nf * 16 + (l & 15);
  float v = (n < NCLASSC) ? W_mlp[n * HDIMC + k] : 0.f;
  short h, lo;
  bsplit(v, &h, &lo);
  wh[i] = h;
  wl[i] = lo;
}

// Fused GEMM1+GEMM2 via MFMA, split-bf16 3-pass.
// Block: 64 nodes x full 256 hdim. 8 waves, wave tile 32x64.
__global__ __launch_bounds__(512, 4) void k_fused_mfma(
    const float* __restrict__ mean, const float* __restrict__ x,
    const short* __restrict__ bmh, const short* __restrict__ bml,
    const short* __restrict__ wmh, const short* __restrict__ wml,
    const float* __restrict__ b_l, const float* __restrict__ b_mlp,
    float* __restrict__ out) {
  __shared__ short sh[32768];  // 64 KB: hi [0,16384), lo [16384,32768); reused for h
  int t = threadIdx.x;
  int m0 = blockIdx.x * 64;

  // ---- stage A = [mean | x] rows m0..m0+63 as bf16 hi/lo, XOR-swizzled ----
#pragma unroll
  for (int r = 0; r < 4; ++r) {
    int c = t + 512 * r;          // chunk id: 64 rows x 32 chunks-of-8
    int row = c >> 5, kc = c & 31;
    int node = m0 + row;
    float4 v0 = make_float4(0.f, 0.f, 0.f, 0.f), v1 = v0;
    if (node < N_NODESC) {
      const float* src = (kc < 16) ? (mean + (size_t)node * 128 + kc * 8)
                                   : (x + (size_t)node * 128 + (kc - 16) * 8);
      v0 = *(const float4*)src;
      v1 = *(const float4*)(src + 4);
    }
    float f[8] = {v0.x, v0.y, v0.z, v0.w, v1.x, v1.y, v1.z, v1.w};
    short8v hi8, lo8;
#pragma unroll
    for (int i = 0; i < 8; ++i) {
      short h, lo;
      bsplit(f[i], &h, &lo);
      hi8[i] = h;
      lo8[i] = lo;
    }
    int sidx = row * 256 + ((kc ^ (row & 7)) << 3);
    *(short8v*)&sh[sidx] = hi8;
    *(short8v*)&sh[16384 + sidx] = lo8;
  }
  __syncthreads();

  int w = t >> 6, l = t & 63;
  int wm = w >> 2, wn = w & 3;   // wave tile: rows wm*32..+32, cols wn*64..+64
  int lr = l & 15, lg = l >> 4;

  float4v acc[2][4];
#pragma unroll
  for (int mi = 0; mi < 2; ++mi)
#pragma unroll
    for (int nj = 0; nj < 4; ++nj) acc[mi][nj] = (float4v){0.f, 0.f, 0.f, 0.f};

  // ---- GEMM1: h = A @ B, K=256 in 8 steps of 32 ----
  for (int ks = 0; ks < 8; ++ks) {
    short8v ah[2], al[2];
#pragma unroll
    for (int mi = 0; mi < 2; ++mi) {
      int row = wm * 32 + mi * 16 + lr;
      int kc = ks * 4 + lg;
      int sidx = row * 256 + ((kc ^ (row & 7)) << 3);
      ah[mi] = *(short8v*)&sh[sidx];
      al[mi] = *(short8v*)&sh[16384 + sidx];
    }
    short8v bh[4], blo[4];
#pragma unroll
    for (int nj = 0; nj < 4; ++nj) {
      int nf = wn * 4 + nj;
      int fi = ((ks * 16 + nf) * 64 + l) * 8;
      bh[nj] = *(const short8v*)&bmh[fi];
      blo[nj] = *(const short8v*)&bml[fi];
    }
#pragma unroll
    for (int mi = 0; mi < 2; ++mi)
#pragma unroll
      for (int nj = 0; nj < 4; ++nj) {
        acc[mi][nj] = __builtin_amdgcn_mfma_f32_16x16x32_bf16(ah[mi], bh[nj], acc[mi][nj], 0, 0, 0);
        acc[mi][nj] = __builtin_amdgcn_mfma_f32_16x16x32_bf16(ah[mi], blo[nj], acc[mi][nj], 0, 0, 0);
        acc[mi][nj] = __builtin_amdgcn_mfma_f32_16x16x32_bf16(al[mi], bh[nj], acc[mi][nj], 0, 0, 0);
      }
  }
  __syncthreads();  // all waves done reading A

  // ---- epilogue 1: h = relu(acc + b_l) -> bf16 hi/lo back into sh ----
#pragma unroll
  for (int mi = 0; mi < 2; ++mi)
#pragma unroll
    for (int nj = 0; nj < 4; ++nj) {
      int col = wn * 64 + nj * 16 + lr;
      float bb = b_l[col];
#pragma unroll
      for (int r = 0; r < 4; ++r) {
        int row = wm * 32 + mi * 16 + lg * 4 + r;
        float v = acc[mi][nj][r] + bb;
        v = fmaxf(v, 0.f);
        short h, lo;
        bsplit(v, &h, &lo);
        int kc2 = col >> 3;
        int sidx = row * 256 + ((kc2 ^ (row & 7)) << 3) + (col & 7);
        sh[sidx] = h;
        sh[16384 + sidx] = lo;
      }
    }
  __syncthreads();

  // ---- GEMM2: out = relu(h) @ Wmlp^T (48 padded cols), K=256 ----
  int mf = w & 3;            // waves 0-3: nf {0,1}; waves 4-7: nf {2}
  float4v a2[2];
  a2[0] = (float4v){0.f, 0.f, 0.f, 0.f};
  a2[1] = a2[0];
  for (int ks = 0; ks < 8; ++ks) {
    int row = mf * 16 + lr;
    int kc = ks * 4 + lg;
    int sidx = row * 256 + ((kc ^ (row & 7)) << 3);
    short8v hh = *(short8v*)&sh[sidx];
    short8v hl = *(short8v*)&sh[16384 + sidx];
#pragma unroll
    for (int u = 0; u < 2; ++u) {
      if (w >= 4 && u > 0) break;
      int nf = (w < 4) ? u : 2;
      int fi = ((ks * 3 + nf) * 64 + l) * 8;
      short8v wh = *(const short8v*)&wmh[fi];
      short8v wlo = *(const short8v*)&wml[fi];
      a2[u] = __builtin_amdgcn_mfma_f32_16x16x32_bf16(hh, wh, a2[u], 0, 0, 0);
      a2[u] = __builtin_amdgcn_mfma_f32_16x16x32_bf16(hl, wh, a2[u], 0, 0, 0);
      a2[u] = __builtin_amdgcn_mfma_f32_16x16x32_bf16(hh, wlo, a2[u], 0, 0, 0);
    }
  }
#pragma unroll
  for (int u = 0; u < 2; ++u) {
    if (w >= 4 && u > 0) break;
    int nf = (w < 4) ? u : 2;
    int col = nf * 16 + lr;
    if (col < NCLASSC) {
      float bb = b_mlp[col];
#pragma unroll
      for (int r = 0; r < 4; ++r) {
        int node = m0 + mf * 16 + lg * 4 + r;
        if (node < N_NODESC) out[node * NCLASSC + col] = a2[u][r] + bb;
      }
    }
  }
}

extern "C" void kernel_launch(void* const* d_in, const int* in_sizes, int n_in,
                              void* d_out, int out_size, void* d_ws, size_t ws_size,
                              hipStream_t stream) {
  const float* x     = (const float*)d_in[0];
  const float* W_l   = (const float*)d_in[1];
  const float* b_l   = (const float*)d_in[2];
  const float* W_r   = (const float*)d_in[3];
  const float* W_mlp = (const float*)d_in[4];
  const float* b_mlp = (const float*)d_in[5];
  const int*   e32   = (const int*)d_in[6];
  int E = in_sizes[6] / 2;
  float* out = (float*)d_out;

  char* ws = (char*)d_ws;
  int* deg     = (int*)(ws + 0);
  int* offs    = (int*)(ws + 200704);
  int* cursor  = (int*)(ws + 401408);
  short* wmh   = (short*)(ws + 401408);  // overlays cursor AFTER k_fill
  short* wml   = (short*)(ws + 425984);
  int* bsum    = (int*)(ws + 602112);
  int* boff    = (int*)(ws + 602624);
  int* flag    = (int*)(ws + 603136);
  short* bmh   = (short*)(ws + 603392);
  short* bml   = (short*)(ws + 734464);
  int* csr     = (int*)(ws + 865536);
  float* mean  = (float*)(ws + 4065536);
  unsigned short* xb = (unsigned short*)(ws + 29665536);
  bool use_bf = (ws_size >= 42465536ull);

  hipMemsetAsync(ws, 0, 200704, stream);  // deg only
  k_detect<<<1, 256, 0, stream>>>(e32, flag);
  int eg = (E + 255) / 256;
  k_count<<<eg, 256, 0, stream>>>(e32, flag, E, deg);
  k_scan_partial<<<98, 512, 0, stream>>>(deg, bsum);
  k_scan_bsum<<<1, 128, 0, stream>>>(bsum, boff);
  k_scan_final<<<98, 512, 0, stream>>>(deg, boff, offs, cursor);
  k_fill<<<eg, 256, 0, stream>>>(e32, flag, E, cursor, csr);
  k_build_b<<<256, 256, 0, stream>>>(W_l, W_r, bmh, bml);
  k_build_w<<<48, 256, 0, stream>>>(W_mlp, wmh, wml);   // cursor dead after k_fill
  if (use_bf) {
    k_xbf16<<<3125, 256, 0, stream>>>(x, xb);
    k_aggregate_bf<<<6250, 512, 0, stream>>>(xb, csr, offs, deg, mean);
  } else {
    k_aggregate_f32<<<6250, 512, 0, stream>>>(x, csr, offs, deg, mean);
  }
  k_fused_mfma<<<782, 512, 0, stream>>>(mean, x, bmh, bml, wmh, wml, b_l, b_mlp, out);
}

// Round 4
// 132.878 us; speedup vs baseline: 4.7448x; 1.4802x over previous
//
#include <hip/hip_runtime.h>

#define N_NODESC 50000
#define NEMBEDC 128
#define HDIMC 256
#define NCLASSC 40
#define NBUCK 196        // ceil(50000/256)
#define BCAP 8192        // bucket capacity (mean ~4082, +64 sigma safe)

typedef short short8v __attribute__((ext_vector_type(8)));
typedef float float4v __attribute__((ext_vector_type(4)));

// ---------------- ws layout (bytes) ----------------
// flag    int           @ 0
// bcursor int[256]      @ 256
// bbase   int[256]      @ 1280
// deg     int[50176]    @ 4096
// offs    int[50176]    @ 204800
// wmh     bf16[12288]   @ 405504
// wml     bf16[12288]   @ 430080
// bmh     bf16[65536]   @ 458752
// bml     bf16[65536]   @ 589824
// csr16   u16[800000]   @ 720896   (ends 2320896)
// bbuf    u32[196*8192] @ 2359296  (ends 8781824)  -- dead after k_bsort
// mean    f32[50000*128]@ 2359296  (ends 27959296) -- aliases bbuf (written later)
// xb      bf16[6400000] @ 27959296 (ends 40759296)

__device__ __forceinline__ void bsplit(float f, short* hi, short* lo) {
  unsigned u = __builtin_bit_cast(unsigned, f);
  unsigned hb = (u + 0x7FFFu + ((u >> 16) & 1u)) >> 16;
  *hi = (short)hb;
  float hf = __builtin_bit_cast(float, hb << 16);
  float r = f - hf;
  unsigned u2 = __builtin_bit_cast(unsigned, r);
  *lo = (short)((u2 + 0x7FFFu + ((u2 >> 16) & 1u)) >> 16);
}

__device__ __forceinline__ float blo(unsigned v) {
  return __builtin_bit_cast(float, v << 16);
}
__device__ __forceinline__ float bhi(unsigned v) {
  return __builtin_bit_cast(float, v & 0xFFFF0000u);
}

__global__ void k_detect(const int* __restrict__ e32, int* __restrict__ flag) {
  __shared__ int any;
  if (threadIdx.x == 0) any = 0;
  __syncthreads();
  int local = 0;
  for (int i = threadIdx.x; i < 2048; i += blockDim.x)
    if (e32[2 * i + 1] != 0) local = 1;
  if (local) atomicOr(&any, 1);
  __syncthreads();
  if (threadIdx.x == 0) *flag = any ? 0 : 1;  // 1 => int64 layout
}

// Bucket scatter: 2048 edges/block, LDS ranks, 196 global atomics/block.
__global__ __launch_bounds__(256) void k_bucket(
    const int* __restrict__ e32, const int* __restrict__ flag, int E,
    int* __restrict__ bcursor, unsigned* __restrict__ bbuf) {
  __shared__ int hist[NBUCK];
  __shared__ int sbase[NBUCK];
  int tid = threadIdx.x;
  if (tid < NBUCK) hist[tid] = 0;
  __syncthreads();
  int is64 = *flag;
  int base = blockIdx.x * 2048;
  unsigned pe[8];
  int rk[8];
#pragma unroll
  for (int j = 0; j < 8; ++j) {
    int e = base + j * 256 + tid;
    pe[j] = 0xFFFFFFFFu;
    rk[j] = 0;
    if (e < E) {
      int src = is64 ? e32[2 * e] : e32[e];
      int dst = is64 ? e32[2 * E + 2 * e] : e32[E + e];
      pe[j] = ((unsigned)dst << 16) | (unsigned)src;
      rk[j] = atomicAdd(&hist[dst >> 8], 1);
    }
  }
  __syncthreads();
  if (tid < NBUCK) sbase[tid] = atomicAdd(&bcursor[tid], hist[tid]);
  __syncthreads();
#pragma unroll
  for (int j = 0; j < 8; ++j) {
    if (pe[j] != 0xFFFFFFFFu) {
      int b = pe[j] >> 24;
      int p = sbase[b] + rk[j];
      if (p < BCAP) bbuf[b * BCAP + p] = pe[j];
    }
  }
}

// Exclusive scan of (clamped) bucket counts -> bbase
__global__ void k_bscan(const int* __restrict__ bcursor, int* __restrict__ bbase) {
  __shared__ int s[256];
  int tid = threadIdx.x;
  int c = (tid < NBUCK) ? bcursor[tid] : 0;
  int v = c < BCAP ? c : BCAP;
  s[tid] = v;
  __syncthreads();
  for (int d = 1; d < 256; d <<= 1) {
    int t = (tid >= d) ? s[tid - d] : 0;
    __syncthreads();
    s[tid] += t;
    __syncthreads();
  }
  if (tid < NBUCK) bbase[tid] = s[tid] - v;
}

// Per-bucket 256-bin counting sort: emits deg, offs, csr16 (coalesced-hot writes).
__global__ __launch_bounds__(256) void k_bsort(
    const unsigned* __restrict__ bbuf, const int* __restrict__ bcursor,
    const int* __restrict__ bbase, int* __restrict__ deg, int* __restrict__ offs,
    unsigned short* __restrict__ csr16) {
  __shared__ int hist[256];
  __shared__ int off[256];
  __shared__ int cur[256];
  int tid = threadIdx.x;
  int b = blockIdx.x;
  int cnt = bcursor[b];
  if (cnt > BCAP) cnt = BCAP;
  int ibase = b * BCAP;
  int cbase = bbase[b];
  hist[tid] = 0;
  __syncthreads();
  for (int i = tid; i < cnt; i += 256) {
    unsigned pe = bbuf[ibase + i];
    atomicAdd(&hist[(pe >> 16) & 255], 1);
  }
  __syncthreads();
  off[tid] = hist[tid];
  __syncthreads();
  for (int d = 1; d < 256; d <<= 1) {
    int t = (tid >= d) ? off[tid - d] : 0;
    __syncthreads();
    off[tid] += t;
    __syncthreads();
  }
  int ex = off[tid] - hist[tid];
  int n = (b << 8) + tid;
  deg[n] = hist[tid];
  offs[n] = cbase + ex;
  cur[tid] = ex;
  __syncthreads();
  for (int i = tid; i < cnt; i += 256) {
    unsigned pe = bbuf[ibase + i];
    int ln = (pe >> 16) & 255;
    int p = atomicAdd(&cur[ln], 1);
    csr16[cbase + p] = (unsigned short)(pe & 0xFFFFu);
  }
}

// x -> bf16 (RN), 8 elems/thread
__global__ void k_xbf16(const float* __restrict__ x, unsigned short* __restrict__ xb) {
  int i = (blockIdx.x * 256 + threadIdx.x) * 8;
  float4 a = *(const float4*)(x + i);
  float4 b = *(const float4*)(x + i + 4);
  float f[8] = {a.x, a.y, a.z, a.w, b.x, b.y, b.z, b.w};
  unsigned h[8];
#pragma unroll
  for (int j = 0; j < 8; ++j) {
    unsigned u = __builtin_bit_cast(unsigned, f[j]);
    h[j] = (u + 0x7FFFu + ((u >> 16) & 1u)) >> 16;
  }
  uint4 o;
  o.x = h[0] | (h[1] << 16);
  o.y = h[2] | (h[3] << 16);
  o.z = h[4] | (h[5] << 16);
  o.w = h[6] | (h[7] << 16);
  *(uint4*)(xb + i) = o;
}

// One wave per node, bf16 gather (256B/row), 4-deep MLP unroll.
__global__ __launch_bounds__(512) void k_aggregate_bf(
    const unsigned short* __restrict__ xb, const unsigned short* __restrict__ csr16,
    const int* __restrict__ offs, const int* __restrict__ deg,
    float* __restrict__ mean) {
  int wave = threadIdx.x >> 6;
  int lane = threadIdx.x & 63;
  int node = blockIdx.x * 8 + wave;
  if (node >= N_NODESC) return;
  int beg = __builtin_amdgcn_readfirstlane(offs[node]);
  int d = __builtin_amdgcn_readfirstlane(deg[node]);
  const unsigned* xw = (const unsigned*)xb;
  float ax = 0.f, ay = 0.f;
  int e = 0;
  for (; e + 4 <= d; e += 4) {
    int s0 = csr16[beg + e + 0];
    int s1 = csr16[beg + e + 1];
    int s2 = csr16[beg + e + 2];
    int s3 = csr16[beg + e + 3];
    unsigned v0 = xw[s0 * 64 + lane];
    unsigned v1 = xw[s1 * 64 + lane];
    unsigned v2 = xw[s2 * 64 + lane];
    unsigned v3 = xw[s3 * 64 + lane];
    ax += blo(v0) + blo(v1) + blo(v2) + blo(v3);
    ay += bhi(v0) + bhi(v1) + bhi(v2) + bhi(v3);
  }
  for (; e < d; ++e) {
    unsigned v = xw[csr16[beg + e] * 64 + lane];
    ax += blo(v);
    ay += bhi(v);
  }
  float inv = 1.0f / (float)(d > 0 ? d : 1);
  float2 r;
  r.x = ax * inv;
  r.y = ay * inv;
  ((float2*)mean)[node * 64 + lane] = r;
}

// Fallback: f32 gather (512B/row), 4-deep MLP unroll.
__global__ __launch_bounds__(512) void k_aggregate_f32(
    const float* __restrict__ x, const unsigned short* __restrict__ csr16,
    const int* __restrict__ offs, const int* __restrict__ deg,
    float* __restrict__ mean) {
  int wave = threadIdx.x >> 6;
  int lane = threadIdx.x & 63;
  int node = blockIdx.x * 8 + wave;
  if (node >= N_NODESC) return;
  int beg = __builtin_amdgcn_readfirstlane(offs[node]);
  int d = __builtin_amdgcn_readfirstlane(deg[node]);
  const float2* x2 = (const float2*)x;
  float ax = 0.f, ay = 0.f;
  int e = 0;
  for (; e + 4 <= d; e += 4) {
    int s0 = csr16[beg + e + 0];
    int s1 = csr16[beg + e + 1];
    int s2 = csr16[beg + e + 2];
    int s3 = csr16[beg + e + 3];
    float2 v0 = x2[s0 * 64 + lane];
    float2 v1 = x2[s1 * 64 + lane];
    float2 v2 = x2[s2 * 64 + lane];
    float2 v3 = x2[s3 * 64 + lane];
    ax += v0.x + v1.x + v2.x + v3.x;
    ay += v0.y + v1.y + v2.y + v3.y;
  }
  for (; e < d; ++e) {
    float2 v = x2[csr16[beg + e] * 64 + lane];
    ax += v.x;
    ay += v.y;
  }
  float inv = 1.0f / (float)(d > 0 ? d : 1);
  float2 r;
  r.x = ax * inv;
  r.y = ay * inv;
  ((float2*)mean)[node * 64 + lane] = r;
}

// B = [W_l | W_r] as bf16 hi/lo in MFMA fragment order:
// elem (ks, nf, lane, e) = B[k = ks*32 + (lane>>4)*8 + e][n = nf*16 + (lane&15)]
__global__ void k_build_b(const float* __restrict__ W_l, const float* __restrict__ W_r,
                          short* __restrict__ bh, short* __restrict__ bl) {
  int i = blockIdx.x * 256 + threadIdx.x;  // < 65536
  int e = i & 7, l = (i >> 3) & 63, nf = (i >> 9) & 15, ks = i >> 13;
  int k = ks * 32 + (l >> 4) * 8 + e;
  int n = nf * 16 + (l & 15);
  float v = (k < 128) ? W_l[n * 128 + k] : W_r[n * 128 + (k - 128)];
  short h, lo;
  bsplit(v, &h, &lo);
  bh[i] = h;
  bl[i] = lo;
}

// W_mlp (padded to 48 rows) as bf16 hi/lo fragment order: [ks(8)][nf(3)][lane][8]
__global__ void k_build_w(const float* __restrict__ W_mlp,
                          short* __restrict__ wh, short* __restrict__ wl) {
  int i = blockIdx.x * 256 + threadIdx.x;  // < 12288
  int e = i & 7, l = (i >> 3) & 63, g = i >> 9;  // g < 24
  int nf = g % 3, ks = g / 3;
  int k = ks * 32 + (l >> 4) * 8 + e;
  int n = nf * 16 + (l & 15);
  float v = (n < NCLASSC) ? W_mlp[n * HDIMC + k] : 0.f;
  short h, lo;
  bsplit(v, &h, &lo);
  wh[i] = h;
  wl[i] = lo;
}

// Fused GEMM1+GEMM2 via MFMA, split-bf16 3-pass.
// Block: 64 nodes x full 256 hdim. 8 waves, wave tile 32x64.
__global__ __launch_bounds__(512, 4) void k_fused_mfma(
    const float* __restrict__ mean, const float* __restrict__ x,
    const short* __restrict__ bmh, const short* __restrict__ bml,
    const short* __restrict__ wmh, const short* __restrict__ wml,
    const float* __restrict__ b_l, const float* __restrict__ b_mlp,
    float* __restrict__ out) {
  __shared__ short sh[32768];  // 64 KB: hi [0,16384), lo [16384,32768); reused for h
  int t = threadIdx.x;
  int m0 = blockIdx.x * 64;

  // ---- stage A = [mean | x] rows m0..m0+63 as bf16 hi/lo, XOR-swizzled ----
#pragma unroll
  for (int r = 0; r < 4; ++r) {
    int c = t + 512 * r;          // chunk id: 64 rows x 32 chunks-of-8
    int row = c >> 5, kc = c & 31;
    int node = m0 + row;
    float4 v0 = make_float4(0.f, 0.f, 0.f, 0.f), v1 = v0;
    if (node < N_NODESC) {
      const float* src = (kc < 16) ? (mean + (size_t)node * 128 + kc * 8)
                                   : (x + (size_t)node * 128 + (kc - 16) * 8);
      v0 = *(const float4*)src;
      v1 = *(const float4*)(src + 4);
    }
    float f[8] = {v0.x, v0.y, v0.z, v0.w, v1.x, v1.y, v1.z, v1.w};
    short8v hi8, lo8;
#pragma unroll
    for (int i = 0; i < 8; ++i) {
      short h, lo;
      bsplit(f[i], &h, &lo);
      hi8[i] = h;
      lo8[i] = lo;
    }
    int sidx = row * 256 + ((kc ^ (row & 7)) << 3);
    *(short8v*)&sh[sidx] = hi8;
    *(short8v*)&sh[16384 + sidx] = lo8;
  }
  __syncthreads();

  int w = t >> 6, l = t & 63;
  int wm = w >> 2, wn = w & 3;   // wave tile: rows wm*32..+32, cols wn*64..+64
  int lr = l & 15, lg = l >> 4;

  float4v acc[2][4];
#pragma unroll
  for (int mi = 0; mi < 2; ++mi)
#pragma unroll
    for (int nj = 0; nj < 4; ++nj) acc[mi][nj] = (float4v){0.f, 0.f, 0.f, 0.f};

  // ---- GEMM1: h = A @ B, K=256 in 8 steps of 32 ----
  for (int ks = 0; ks < 8; ++ks) {
    short8v ah[2], al[2];
#pragma unroll
    for (int mi = 0; mi < 2; ++mi) {
      int row = wm * 32 + mi * 16 + lr;
      int kc = ks * 4 + lg;
      int sidx = row * 256 + ((kc ^ (row & 7)) << 3);
      ah[mi] = *(short8v*)&sh[sidx];
      al[mi] = *(short8v*)&sh[16384 + sidx];
    }
    short8v bh[4], blo[4];
#pragma unroll
    for (int nj = 0; nj < 4; ++nj) {
      int nf = wn * 4 + nj;
      int fi = ((ks * 16 + nf) * 64 + l) * 8;
      bh[nj] = *(const short8v*)&bmh[fi];
      blo[nj] = *(const short8v*)&bml[fi];
    }
#pragma unroll
    for (int mi = 0; mi < 2; ++mi)
#pragma unroll
      for (int nj = 0; nj < 4; ++nj) {
        acc[mi][nj] = __builtin_amdgcn_mfma_f32_16x16x32_bf16(ah[mi], bh[nj], acc[mi][nj], 0, 0, 0);
        acc[mi][nj] = __builtin_amdgcn_mfma_f32_16x16x32_bf16(ah[mi], blo[nj], acc[mi][nj], 0, 0, 0);
        acc[mi][nj] = __builtin_amdgcn_mfma_f32_16x16x32_bf16(al[mi], bh[nj], acc[mi][nj], 0, 0, 0);
      }
  }
  __syncthreads();  // all waves done reading A

  // ---- epilogue 1: h = relu(acc + b_l) -> bf16 hi/lo back into sh ----
#pragma unroll
  for (int mi = 0; mi < 2; ++mi)
#pragma unroll
    for (int nj = 0; nj < 4; ++nj) {
      int col = wn * 64 + nj * 16 + lr;
      float bb = b_l[col];
#pragma unroll
      for (int r = 0; r < 4; ++r) {
        int row = wm * 32 + mi * 16 + lg * 4 + r;
        float v = acc[mi][nj][r] + bb;
        v = fmaxf(v, 0.f);
        short h, lo;
        bsplit(v, &h, &lo);
        int kc2 = col >> 3;
        int sidx = row * 256 + ((kc2 ^ (row & 7)) << 3) + (col & 7);
        sh[sidx] = h;
        sh[16384 + sidx] = lo;
      }
    }
  __syncthreads();

  // ---- GEMM2: out = relu(h) @ Wmlp^T (48 padded cols), K=256 ----
  int mf = w & 3;            // waves 0-3: nf {0,1}; waves 4-7: nf {2}
  float4v a2[2];
  a2[0] = (float4v){0.f, 0.f, 0.f, 0.f};
  a2[1] = a2[0];
  for (int ks = 0; ks < 8; ++ks) {
    int row = mf * 16 + lr;
    int kc = ks * 4 + lg;
    int sidx = row * 256 + ((kc ^ (row & 7)) << 3);
    short8v hh = *(short8v*)&sh[sidx];
    short8v hl = *(short8v*)&sh[16384 + sidx];
#pragma unroll
    for (int u = 0; u < 2; ++u) {
      if (w >= 4 && u > 0) break;
      int nf = (w < 4) ? u : 2;
      int fi = ((ks * 3 + nf) * 64 + l) * 8;
      short8v wh = *(const short8v*)&wmh[fi];
      short8v wlo = *(const short8v*)&wml[fi];
      a2[u] = __builtin_amdgcn_mfma_f32_16x16x32_bf16(hh, wh, a2[u], 0, 0, 0);
      a2[u] = __builtin_amdgcn_mfma_f32_16x16x32_bf16(hl, wh, a2[u], 0, 0, 0);
      a2[u] = __builtin_amdgcn_mfma_f32_16x16x32_bf16(hh, wlo, a2[u], 0, 0, 0);
    }
  }
#pragma unroll
  for (int u = 0; u < 2; ++u) {
    if (w >= 4 && u > 0) break;
    int nf = (w < 4) ? u : 2;
    int col = nf * 16 + lr;
    if (col < NCLASSC) {
      float bb = b_mlp[col];
#pragma unroll
      for (int r = 0; r < 4; ++r) {
        int node = m0 + mf * 16 + lg * 4 + r;
        if (node < N_NODESC) out[node * NCLASSC + col] = a2[u][r] + bb;
      }
    }
  }
}

extern "C" void kernel_launch(void* const* d_in, const int* in_sizes, int n_in,
                              void* d_out, int out_size, void* d_ws, size_t ws_size,
                              hipStream_t stream) {
  const float* x     = (const float*)d_in[0];
  const float* W_l   = (const float*)d_in[1];
  const float* b_l   = (const float*)d_in[2];
  const float* W_r   = (const float*)d_in[3];
  const float* W_mlp = (const float*)d_in[4];
  const float* b_mlp = (const float*)d_in[5];
  const int*   e32   = (const int*)d_in[6];
  int E = in_sizes[6] / 2;
  float* out = (float*)d_out;

  char* ws = (char*)d_ws;
  int* flag        = (int*)(ws + 0);
  int* bcursor     = (int*)(ws + 256);
  int* bbase       = (int*)(ws + 1280);
  int* deg         = (int*)(ws + 4096);
  int* offs        = (int*)(ws + 204800);
  short* wmh       = (short*)(ws + 405504);
  short* wml       = (short*)(ws + 430080);
  short* bmh       = (short*)(ws + 458752);
  short* bml       = (short*)(ws + 589824);
  unsigned short* csr16 = (unsigned short*)(ws + 720896);
  unsigned* bbuf   = (unsigned*)(ws + 2359296);
  float* mean      = (float*)(ws + 2359296);   // aliases bbuf (bbuf dead first)
  unsigned short* xb = (unsigned short*)(ws + 27959296);
  bool use_bf = (ws_size >= 40759296ull);

  hipMemsetAsync(ws, 0, 2304, stream);  // flag + bcursor + bbase
  k_detect<<<1, 256, 0, stream>>>(e32, flag);
  int bg = (E + 2047) / 2048;
  k_bucket<<<bg, 256, 0, stream>>>(e32, flag, E, bcursor, bbuf);
  k_bscan<<<1, 256, 0, stream>>>(bcursor, bbase);
  k_bsort<<<NBUCK, 256, 0, stream>>>(bbuf, bcursor, bbase, deg, offs, csr16);
  k_build_b<<<256, 256, 0, stream>>>(W_l, W_r, bmh, bml);
  k_build_w<<<48, 256, 0, stream>>>(W_mlp, wmh, wml);
  if (use_bf) {
    k_xbf16<<<3125, 256, 0, stream>>>(x, xb);
    k_aggregate_bf<<<6250, 512, 0, stream>>>(xb, csr16, offs, deg, mean);
  } else {
    k_aggregate_f32<<<6250, 512, 0, stream>>>(x, csr16, offs, deg, mean);
  }
  k_fused_mfma<<<782, 512, 0, stream>>>(mean, x, bmh, bml, wmh, wml, b_l, b_mlp, out);
}